// Round 10
// baseline (317.695 us; speedup 1.0000x reference)
//
#include <hip/hip_runtime.h>
#include <cstdint>
#include <cstddef>

// ---------------------------------------------------------------------------
// GatingNetwork r10: 32x32x16 MFMA (82us floor vs 99us) with all verified
// pieces: r7's B step-images + epilogue (HW-verified), rolling 2-set B pipe,
// raw lgkm-only barriers, K=64 supers. New: padded fragment-major A-slab
// (kslot stride 520 halves -> conflict-free reads, 2-way writes; fixes r8's
// 8-way read + r9's 8-way write conflicts), 2 images only (ahs via pk_mul --
// true VALU is negligible: VALUBusy ~= MfmaUtil + eps across r1-r9, MFMA
// issue counts as VALU busy), spacing-1 acc rotation (pipe-sharing covers).
// Numerics: A=64x hi/lo fp16, B=64w hi/lo fp16 (lo x2^8); 3-product
// Markidis; h at scale 2^12; fused LN/erf-GELU/top2/lb-loss.
// ---------------------------------------------------------------------------

typedef _Float16 f16;
typedef _Float16 f16x8 __attribute__((ext_vector_type(8)));
typedef float f32x16 __attribute__((ext_vector_type(16)));

#define B_ROWS 65536
#define D_DIM 1024
#define H_DIM 512
#define E_DIM 8
#define BM 64
#define THREADS 512
#define NSUPER 16                        // 16 supers x K64 (4 ksteps each)
#define KSTRIDE 520                      // halves per kslot (1040 B: bank-shift 4)
#define IMGH (8 * KSTRIDE)               // 4160 halves per image per buffer
#define BUFH (2 * IMGH)                  // 8320 halves per buffer (hi+lo)
#define STEPH (H_DIM * 16)               // 8192 halves per K=16 B step image
#define IMG_TOTAL (64 * STEPH)           // 524288 halves = 1 MB per image
#define GACC_OFF ((size_t)2 * IMG_TOTAL * sizeof(f16))  // 2 MB

// ---- prep: split W1 into fp16 hi/lo step-images in 32x32 B-fragment order --
// (r7 HW-verified) img[s][col][k']: lane reads col*16 + (lane>>5)*8.
__global__ void prep_split(const float* __restrict__ W1,
                           f16* __restrict__ wh, f16* __restrict__ wl) {
  int id = blockIdx.x * 256 + threadIdx.x;   // 65536 threads
  int h = id & (H_DIM - 1);
  int kg = id >> 9;                          // 0..127
  int k0 = kg * 8;
  int s = k0 >> 4;                           // 0..63
  int ko = k0 & 15;                          // 0 or 8
  f16x8 hv, lv;
#pragma unroll
  for (int j = 0; j < 8; ++j) {
    float v = W1[(size_t)(k0 + j) * H_DIM + h] * 64.0f;
    f16 hi = (f16)v;
    hv[j] = hi;
    lv[j] = (f16)((v - (float)hi) * 256.0f);  // residual pre-scaled 2^8
  }
  size_t o = (size_t)s * STEPH + (size_t)h * 16 + ko;
  *(f16x8*)&wh[o] = hv;
  *(f16x8*)&wl[o] = lv;
}

__global__ void zero_acc(float* __restrict__ acc) {
  if (threadIdx.x < 16) acc[threadIdx.x] = 0.0f;
}

// ---- main fused kernel -----------------------------------------------------
__global__ __launch_bounds__(THREADS, 4) void fused_main(
    const float* __restrict__ x,
    const f16* __restrict__ wh, const f16* __restrict__ wl,
    const float* __restrict__ b1, const float* __restrict__ lnw,
    const float* __restrict__ lnb, const float* __restrict__ W2,
    const float* __restrict__ b2, float* __restrict__ out,
    float* __restrict__ gacc) {
  // GEMM: 2 buffers x (hi+lo) x 8320 halves = 33280 B. Epilogue overlays 21056.
  __shared__ __align__(16) char pool[33280];
  f16* sx = (f16*)pool;

  const int tid = threadIdx.x;
  const int lane = tid & 63;
  const int wv = tid >> 6;        // 0..7 : wave owns cols wv*64..+63, all 64 rows
  const int l31 = lane & 31;
  const int hi5 = lane >> 5;      // 0..1
  const int64_t row0 = (int64_t)blockIdx.x * BM;

  // staging: thread (srow = tid>>3, kslot = tid&7) stages k = kslot*8..+7
  const int srow = tid >> 3;
  const int kslot = tid & 7;
  const int swo = kslot * KSTRIDE + srow * 8;
  const float* xbase = x + (row0 + srow) * D_DIM + kslot * 8;

  // A-read lane offset: kslot = ks*2 + hi5, row = mt*32 + l31
  const int aro = hi5 * KSTRIDE + l31 * 8;         // + ks*1040 + mt*256 + buf

  // B lane base within a step image (32x32 fragment order, r7-verified)
  const f16* whp = wh + (wv * 64 + l31) * 16 + hi5 * 8;

  f32x16 acc[2][2];
#pragma unroll
  for (int mt = 0; mt < 2; ++mt)
#pragma unroll
    for (int nt = 0; nt < 2; ++nt)
#pragma unroll
      for (int r = 0; r < 16; ++r) acc[mt][nt][r] = 0.0f;

  // two k-step B register sets: [set][0..1]=hi (nt0,nt1), [2..3]=lo
  f16x8 setB[2][4];

#define ISSUE(si, G)                                                          \
  do {                                                                        \
    const f16* p = whp + (size_t)((G) & 63) * STEPH;                          \
    setB[si][0] = *(const f16x8*)(p);                                         \
    setB[si][1] = *(const f16x8*)(p + 512);                                   \
    setB[si][2] = *(const f16x8*)(p + IMG_TOTAL);                             \
    setB[si][3] = *(const f16x8*)(p + IMG_TOTAL + 512);                       \
  } while (0)

  // per mt: 2 conflict-free ds_read_b128 + 4 pk_mul, 6 MFMAs with spacing-1
  // acc rotation (inter-wave pipe sharing covers the latency).
#define KSTEP(si, ks, bufv)                                                   \
  do {                                                                        \
    __builtin_amdgcn_s_setprio(1);                                            \
    _Pragma("unroll") for (int mt = 0; mt < 2; ++mt) {                        \
      const int ao = (bufv)*BUFH + (ks)*1040 + mt * 256 + aro;                \
      f16x8 ah = *(const f16x8*)&sx[ao];                                      \
      f16x8 al = *(const f16x8*)&sx[ao + IMGH];                               \
      f16x8 ahs;                                                              \
      _Pragma("unroll") for (int q = 0; q < 8; ++q) ahs[q] =                  \
          ah[q] * (f16)0.00390625f;                                           \
      acc[mt][0] = __builtin_amdgcn_mfma_f32_32x32x16_f16(                    \
          ah, setB[si][0], acc[mt][0], 0, 0, 0);                              \
      acc[mt][1] = __builtin_amdgcn_mfma_f32_32x32x16_f16(                    \
          ah, setB[si][1], acc[mt][1], 0, 0, 0);                              \
      acc[mt][0] = __builtin_amdgcn_mfma_f32_32x32x16_f16(                    \
          al, setB[si][0], acc[mt][0], 0, 0, 0);                              \
      acc[mt][1] = __builtin_amdgcn_mfma_f32_32x32x16_f16(                    \
          al, setB[si][1], acc[mt][1], 0, 0, 0);                              \
      acc[mt][0] = __builtin_amdgcn_mfma_f32_32x32x16_f16(                    \
          ahs, setB[si][2], acc[mt][0], 0, 0, 0);                             \
      acc[mt][1] = __builtin_amdgcn_mfma_f32_32x32x16_f16(                    \
          ahs, setB[si][3], acc[mt][1], 0, 0, 0);                             \
    }                                                                         \
    __builtin_amdgcn_s_setprio(0);                                            \
  } while (0)

#define WRITE_SLAB(bufv)                                                      \
  do {                                                                        \
    float vv[8] = {xv0.x, xv0.y, xv0.z, xv0.w, xv1.x, xv1.y, xv1.z, xv1.w};   \
    f16x8 hv, lv;                                                             \
    _Pragma("unroll") for (int q = 0; q < 8; ++q) {                           \
      float t = vv[q] * 64.0f;                                                \
      f16 hh = (f16)t;                                                        \
      hv[q] = hh;                                                             \
      lv[q] = (f16)(t - (float)hh);                                           \
    }                                                                         \
    *(f16x8*)&sx[(bufv)*BUFH + swo] = hv;                                     \
    *(f16x8*)&sx[(bufv)*BUFH + IMGH + swo] = lv;                              \
  } while (0)

  // raw barrier: drain only LDS ops, keep global loads in flight (T4)
#define SLAB_BARRIER()                                                        \
  do {                                                                        \
    asm volatile("s_waitcnt lgkmcnt(0)" ::: "memory");                        \
    __builtin_amdgcn_s_barrier();                                             \
    __builtin_amdgcn_sched_barrier(0);                                        \
  } while (0)

  // ---- prologue: slab super0, B sets for ksteps 0/1, xv <- super1 ---------
  float4 xv0 = *(const float4*)(xbase);
  float4 xv1 = *(const float4*)(xbase + 4);
  WRITE_SLAB(0);
  ISSUE(0, 0);
  ISSUE(1, 1);
  xv0 = *(const float4*)(xbase + 64);
  xv1 = *(const float4*)(xbase + 68);
  SLAB_BARRIER();

  for (int s = 0; s < NSUPER; ++s) {
    const int buf = s & 1;
    KSTEP(0, 0, buf);             // kstep 4s   (set issued >=1 kstep ago)
    ISSUE(0, 4 * s + 2);          // refill set0 for kstep 4s+2
    KSTEP(1, 1, buf);
    ISSUE(1, 4 * s + 3);
    KSTEP(0, 2, buf);
    ISSUE(0, 4 * s + 4);          // next super's kstep 0 (crosses barrier)
    KSTEP(1, 3, buf);
    ISSUE(1, 4 * s + 5);
    WRITE_SLAB(buf ^ 1);          // slab for super s+1 (xv loaded last iter)
    xv0 = *(const float4*)(xbase + (((s + 2) & 15) * 64));   // x for super s+2
    xv1 = *(const float4*)(xbase + (((s + 2) & 15) * 64) + 4);
    SLAB_BARRIER();
  }
#undef ISSUE
#undef KSTEP
#undef WRITE_SLAB
#undef SLAB_BARRIER
  __syncthreads();  // full drain before overlaying epilogue LDS

  // ---------------- epilogue (h at scale 2^12; r7 HW-verified) --------------
  // C/D map: row = (reg&3) + 8*(reg>>2) + 4*hi5 + 32*mt, col = wv*64+nt*32+l31
  float* eStat = (float*)pool;             // [8][64][2] = 4096 B
  float* eLog = (float*)(pool + 4096);     // [8][64][8] = 16384 B
  float* eMu = (float*)(pool + 20480);     // [64]
  float* eRs = (float*)(pool + 20736);     // [64]
  float* eFP = (float*)(pool + 20992);     // [16]

  // per-column params from L2 (2 cols per thread)
  float bb[2], lw[2], lb[2];
  float4 w2a[2], w2b[2];
#pragma unroll
  for (int nt = 0; nt < 2; ++nt) {
    int col = wv * 64 + nt * 32 + l31;
    bb[nt] = b1[col] * 4096.0f;
    lw[nt] = lnw[col];
    lb[nt] = lnb[col];
    w2a[nt] = *(const float4*)&W2[col * 8];
    w2b[nt] = *(const float4*)&W2[col * 8 + 4];
  }
  if (tid < 16) eFP[tid] = 0.0f;

  // h += b1 (scaled)
#pragma unroll
  for (int mt = 0; mt < 2; ++mt)
#pragma unroll
    for (int nt = 0; nt < 2; ++nt)
#pragma unroll
      for (int r = 0; r < 16; ++r) acc[mt][nt][r] += bb[nt];

  // row stats: per (mt, q-group of 4 regs), 5-step shfl over l31, write once
#pragma unroll
  for (int mt = 0; mt < 2; ++mt)
#pragma unroll
    for (int q = 0; q < 4; ++q) {
      float s1[4], s2[4];
#pragma unroll
      for (int r = 0; r < 4; ++r) {
        float v0 = acc[mt][0][q * 4 + r];
        float v1 = acc[mt][1][q * 4 + r];
        s1[r] = v0 + v1;
        s2[r] = fmaf(v0, v0, v1 * v1);
      }
#pragma unroll
      for (int d = 1; d < 32; d <<= 1)
#pragma unroll
        for (int r = 0; r < 4; ++r) {
          s1[r] += __shfl_xor(s1[r], d);
          s2[r] += __shfl_xor(s2[r], d);
        }
      if (l31 == 0) {
        int rb = 8 * q + 4 * hi5 + 32 * mt;
#pragma unroll
        for (int r = 0; r < 4; ++r) {
          eStat[(wv * 64 + rb + r) * 2 + 0] = s1[r];
          eStat[(wv * 64 + rb + r) * 2 + 1] = s2[r];
        }
      }
    }
  __syncthreads();
  if (tid < BM) {
    float s1 = 0.0f, s2 = 0.0f;
#pragma unroll
    for (int w = 0; w < 8; ++w) {
      s1 += eStat[(w * 64 + tid) * 2 + 0];
      s2 += eStat[(w * 64 + tid) * 2 + 1];
    }
    float mu = s1 * (1.0f / 512.0f);
    float var = s2 * (1.0f / 512.0f) - mu * mu;
    eMu[tid] = mu;
    eRs[tid] = 1.0f / sqrtf(var + (1e-5f * 4096.0f * 4096.0f));
  }
  __syncthreads();

  // LN + exact-erf GELU + per-wave partial logits (per-row, 5-step shfl)
#pragma unroll
  for (int mt = 0; mt < 2; ++mt)
#pragma unroll
    for (int q = 0; q < 4; ++q)
#pragma unroll
      for (int r = 0; r < 4; ++r) {
        const int reg = q * 4 + r;
        const int row = r + 8 * q + 4 * hi5 + 32 * mt;
        float mu_r = eMu[row];
        float rs_r = eRs[row];
        float lg[8];
#pragma unroll
        for (int e = 0; e < 8; ++e) lg[e] = 0.0f;
#pragma unroll
        for (int nt = 0; nt < 2; ++nt) {
          float hn = (acc[mt][nt][reg] - mu_r) * rs_r;
          float y = fmaf(hn, lw[nt], lb[nt]);
          float g = 0.5f * y * (1.0f + erff(y * 0.70710678118654752440f));
          lg[0] = fmaf(g, w2a[nt].x, lg[0]);
          lg[1] = fmaf(g, w2a[nt].y, lg[1]);
          lg[2] = fmaf(g, w2a[nt].z, lg[2]);
          lg[3] = fmaf(g, w2a[nt].w, lg[3]);
          lg[4] = fmaf(g, w2b[nt].x, lg[4]);
          lg[5] = fmaf(g, w2b[nt].y, lg[5]);
          lg[6] = fmaf(g, w2b[nt].z, lg[6]);
          lg[7] = fmaf(g, w2b[nt].w, lg[7]);
        }
#pragma unroll
        for (int d = 1; d < 32; d <<= 1)
#pragma unroll
          for (int e = 0; e < 8; ++e) lg[e] += __shfl_xor(lg[e], d);
        if (l31 == 0) {
#pragma unroll
          for (int e = 0; e < 8; ++e) eLog[(wv * 64 + row) * 8 + e] = lg[e];
        }
      }
  __syncthreads();

  // top-2 + sparse softmax + write + load-balance partials
  if (tid < BM) {
    float v[8];
#pragma unroll
    for (int e = 0; e < 8; ++e) {
      float s = b2[e];
#pragma unroll
      for (int w = 0; w < 8; ++w) s += eLog[(w * 64 + tid) * 8 + e];
      v[e] = s;
    }
    float m1 = v[0];
    int i1 = 0;
#pragma unroll
    for (int e = 1; e < 8; ++e)
      if (v[e] > m1) { m1 = v[e]; i1 = e; }   // strict >: lowest index wins ties
    float m2 = -3.0e38f;
    int i2 = -1;
#pragma unroll
    for (int e = 0; e < 8; ++e)
      if (e != i1 && v[e] > m2) { m2 = v[e]; i2 = e; }
    float dd = expf(m2 - m1);
    float inv = 1.0f / (1.0f + dd);
    float wA = inv, wB = dd * inv;
    float o[8];
#pragma unroll
    for (int e = 0; e < 8; ++e)
      o[e] = (e == i1) ? wA : ((e == i2) ? wB : 0.0f);
    float4* op = (float4*)&out[(row0 + tid) * 8];
    op[0] = (float4){o[0], o[1], o[2], o[3]};
    op[1] = (float4){o[4], o[5], o[6], o[7]};
    atomicAdd(&eFP[i1], 1.0f);
    atomicAdd(&eFP[i2], 1.0f);
    atomicAdd(&eFP[8 + i1], wA);
    atomicAdd(&eFP[8 + i2], wB);
  }
  __syncthreads();
  if (tid < 16) atomicAdd(&gacc[tid], eFP[tid]);
}

// ---- finalize load-balance loss --------------------------------------------
__global__ void lb_final(const float* __restrict__ gacc, float* __restrict__ out) {
  if (threadIdx.x == 0) {
    const float invB = 1.0f / 65536.0f;
    float s = 0.0f;
#pragma unroll
    for (int e = 0; e < 8; ++e) s += (gacc[e] * invB) * (gacc[8 + e] * invB);
    out[(size_t)B_ROWS * E_DIM] = 0.01f * 8.0f * s;
  }
}

// ---- launch ----------------------------------------------------------------
extern "C" void kernel_launch(void* const* d_in, const int* in_sizes, int n_in,
                              void* d_out, int out_size, void* d_ws, size_t ws_size,
                              hipStream_t stream) {
  (void)in_sizes; (void)n_in; (void)out_size; (void)ws_size;
  const float* x = (const float*)d_in[0];
  const float* W1 = (const float*)d_in[1];
  const float* b1 = (const float*)d_in[2];
  const float* lnw = (const float*)d_in[3];
  const float* lnb = (const float*)d_in[4];
  const float* W2 = (const float*)d_in[5];
  const float* b2 = (const float*)d_in[6];
  float* out = (float*)d_out;
  f16* wh = (f16*)d_ws;
  f16* wl = wh + IMG_TOTAL;
  float* gacc = (float*)((char*)d_ws + GACC_OFF);  // ws needs ~2.1 MB

  zero_acc<<<1, 64, 0, stream>>>(gacc);
  prep_split<<<(D_DIM * H_DIM / 8) / 256, 256, 0, stream>>>(W1, wh, wl);
  fused_main<<<B_ROWS / BM, THREADS, 0, stream>>>(x, wh, wl, b1, lnw, lnb, W2, b2,
                                                  out, gacc);
  lb_final<<<1, 64, 0, stream>>>(gacc, out);
}

// Round 11
// 271.862 us; speedup vs baseline: 1.1686x; 1.1686x over previous
//
#include <hip/hip_runtime.h>
#include <cstdint>
#include <cstddef>

// ---------------------------------------------------------------------------
// GatingNetwork r11: R8 engine (16x16x32 Markidis-3, rolling 2-set B pipe,
// raw lgkm-only barriers, K=64 supers, 64 VGPR + 64 AGPR -> 4 waves/SIMD)
// + de-phased wave schedules: odd waves run chunk-halves AND m-order rotated
// (compile-time clones) so ds_read phases of half the waves overlap MFMA
// phases of the other half (serial-pipe-sum -> max-pipe). WRITE_SLAB moved
// to super top (buffer was drained at the previous barrier) so the pre-
// barrier lgkm drain finds nothing outstanding.
// Numerics (r1-r10 verified): A=64x hi/lo fp16, B=64w hi/lo fp16 (lo x2^8);
// 3-product MFMA; h at scale 2^12; fused LN/erf-GELU/top2/lb-loss.
// ---------------------------------------------------------------------------

typedef _Float16 f16;
typedef _Float16 f16x8 __attribute__((ext_vector_type(8)));
typedef float f32x4 __attribute__((ext_vector_type(4)));

#define B_ROWS 65536
#define D_DIM 1024
#define H_DIM 512
#define E_DIM 8
#define BM 64
#define BK 32
#define THREADS 512
#define NSUPER 16                        // 16 supers x K64 (2 chunks each)
#define LDPX 72                          // slab row stride in halves (144 B)
#define SLABH 4608                       // 64 rows x 72 halves (one image)
#define BUFH 9216                        // hi + lo per buffer
#define IMG_CH (H_DIM * BK)              // 16384 halves per K-chunk B image
#define IMG_TOTAL (32 * IMG_CH)          // 1 MB per image
#define GACC_OFF ((size_t)2 * IMG_TOTAL * sizeof(f16))  // 2 MB

// ---- prep: split W1 into fp16 hi/lo images in MFMA B-fragment order --------
__global__ void prep_split(const float* __restrict__ W1,
                           f16* __restrict__ wh, f16* __restrict__ wl) {
  int id = blockIdx.x * 256 + threadIdx.x;   // 65536 threads
  int h = id & (H_DIM - 1);
  int kg = id >> 9;                          // 0..127
  int c = kg >> 2;
  int kk0 = (kg & 3) * 8;
  int k0 = kg * 8;
  f16x8 hv, lv;
#pragma unroll
  for (int j = 0; j < 8; ++j) {
    float v = W1[(size_t)(k0 + j) * H_DIM + h] * 64.0f;
    f16 hi = (f16)v;
    hv[j] = hi;
    lv[j] = (f16)((v - (float)hi) * 256.0f);  // residual pre-scaled 2^8
  }
  size_t o = (size_t)c * IMG_CH + (size_t)h * BK + kk0;
  *(f16x8*)&wh[o] = hv;
  *(f16x8*)&wl[o] = lv;
}

__global__ void zero_acc(float* __restrict__ acc) {
  if (threadIdx.x < 16) acc[threadIdx.x] = 0.0f;
}

// ---- main fused kernel -----------------------------------------------------
__global__ __launch_bounds__(THREADS, 4) void fused_main(
    const float* __restrict__ x,
    const f16* __restrict__ wh, const f16* __restrict__ wl,
    const float* __restrict__ b1, const float* __restrict__ lnw,
    const float* __restrict__ lnb, const float* __restrict__ W2,
    const float* __restrict__ b2, float* __restrict__ out,
    float* __restrict__ gacc) {
  // GEMM uses [0,36864) (2 K=64 x-slab buffers). Epilogue overlays [0,45632).
  __shared__ __align__(16) char pool[45632];
  f16* sx = (f16*)pool;

  const int tid = threadIdx.x;
  const int lane = tid & 63;
  const int wv = tid >> 6;        // 0..7 : wave owns cols wv*64..+63, all 64 rows
  const int l15 = lane & 15;
  const int l4 = lane >> 4;       // 0..3
  const int64_t row0 = (int64_t)blockIdx.x * BM;

  // staging: thread stages row tid>>3, 8 floats at k-offset (tid&7)*8
  const int srow = tid >> 3;
  const int sk = (tid & 7) * 8;
  const int swo = srow * LDPX + sk;
  const float* xbase = x + (row0 + srow) * D_DIM + sk;

  // B lane base (fragment-order image, r2-verified)
  const f16* whp = wh + (wv * 64 + l15) * BK + l4 * 8;

  f32x4 acc[4][4];
#pragma unroll
  for (int m = 0; m < 4; ++m)
#pragma unroll
    for (int n = 0; n < 4; ++n) acc[m][n] = (f32x4){0.f, 0.f, 0.f, 0.f};

  // two half-chunk B register sets: [set][0..1]=hi frags, [2..3]=lo frags
  f16x8 setB[2][4];

#define ISSUE(si, C, half)                                                    \
  do {                                                                        \
    const f16* p = whp + (size_t)((C) & 31) * IMG_CH + (half) * 1024;         \
    setB[si][0] = *(const f16x8*)(p);                                         \
    setB[si][1] = *(const f16x8*)(p + 512);                                   \
    setB[si][2] = *(const f16x8*)(p + IMG_TOTAL);                             \
    setB[si][3] = *(const f16x8*)(p + IMG_TOTAL + 512);                       \
  } while (0)

  // one m-row of a chunk-half: 2 ds_read_b128 + pk_mul + 6 MFMA (alt-acc)
#define CH_M(si, nh, ch, bufv, MM)                                            \
  do {                                                                        \
    const int ao = (bufv)*BUFH + ((MM)*16 + l15) * LDPX + (ch)*32 + l4 * 8;   \
    f16x8 ah = *(const f16x8*)&sx[ao];                                        \
    f16x8 al = *(const f16x8*)&sx[ao + SLABH];                                \
    f16x8 ahs;                                                                \
    _Pragma("unroll") for (int q = 0; q < 8; ++q) ahs[q] =                    \
        ah[q] * (f16)0.00390625f;                                             \
    acc[MM][(nh)*2 + 0] = __builtin_amdgcn_mfma_f32_16x16x32_f16(             \
        ah, setB[si][0], acc[MM][(nh)*2 + 0], 0, 0, 0);                       \
    acc[MM][(nh)*2 + 1] = __builtin_amdgcn_mfma_f32_16x16x32_f16(             \
        ah, setB[si][1], acc[MM][(nh)*2 + 1], 0, 0, 0);                       \
    acc[MM][(nh)*2 + 0] = __builtin_amdgcn_mfma_f32_16x16x32_f16(             \
        al, setB[si][0], acc[MM][(nh)*2 + 0], 0, 0, 0);                       \
    acc[MM][(nh)*2 + 1] = __builtin_amdgcn_mfma_f32_16x16x32_f16(             \
        al, setB[si][1], acc[MM][(nh)*2 + 1], 0, 0, 0);                       \
    acc[MM][(nh)*2 + 0] = __builtin_amdgcn_mfma_f32_16x16x32_f16(             \
        ahs, setB[si][2], acc[MM][(nh)*2 + 0], 0, 0, 0);                      \
    acc[MM][(nh)*2 + 1] = __builtin_amdgcn_mfma_f32_16x16x32_f16(             \
        ahs, setB[si][3], acc[MM][(nh)*2 + 1], 0, 0, 0);                      \
  } while (0)

#define CHUNK_HALF(si, nh, ch, bufv, MA, MB, MC, MD)                          \
  do {                                                                        \
    __builtin_amdgcn_s_setprio(1);                                            \
    CH_M(si, nh, ch, bufv, MA);                                               \
    CH_M(si, nh, ch, bufv, MB);                                               \
    CH_M(si, nh, ch, bufv, MC);                                               \
    CH_M(si, nh, ch, bufv, MD);                                               \
    __builtin_amdgcn_s_setprio(0);                                            \
  } while (0)

#define WRITE_SLAB(bufv)                                                      \
  do {                                                                        \
    float vv[8] = {xv0.x, xv0.y, xv0.z, xv0.w, xv1.x, xv1.y, xv1.z, xv1.w};   \
    f16x8 hv, lv;                                                             \
    _Pragma("unroll") for (int q = 0; q < 8; ++q) {                           \
      float t = vv[q] * 64.0f;                                                \
      f16 hh = (f16)t;                                                        \
      hv[q] = hh;                                                             \
      lv[q] = (f16)(t - (float)hh);                                           \
    }                                                                         \
    *(f16x8*)&sx[(bufv)*BUFH + swo] = hv;                                     \
    *(f16x8*)&sx[(bufv)*BUFH + SLABH + swo] = lv;                             \
  } while (0)

  // raw barrier: drain only LDS ops, keep global loads in flight (T4)
#define SLAB_BARRIER()                                                        \
  do {                                                                        \
    asm volatile("s_waitcnt lgkmcnt(0)" ::: "memory");                        \
    __builtin_amdgcn_s_barrier();                                             \
    __builtin_amdgcn_sched_barrier(0);                                        \
  } while (0)

  const bool oddw = (wv & 1) != 0;

  // ---- prologue: slab super0; per-clone B sets (even: chunk0, odd: chunk1);
  //      xv <- super1 -----------------------------------------------------
  float4 xv0 = *(const float4*)(xbase);
  float4 xv1 = *(const float4*)(xbase + 4);
  WRITE_SLAB(0);
  if (!oddw) {
    ISSUE(0, 0, 0);
    ISSUE(1, 0, 1);
  } else {
    ISSUE(0, 1, 0);
    ISSUE(1, 1, 1);
  }
  xv0 = *(const float4*)(xbase + 64);
  xv1 = *(const float4*)(xbase + 68);
  SLAB_BARRIER();

  for (int s = 0; s < NSUPER; ++s) {
    const int buf = s & 1;
    // early slab write: target buffer was fully drained at the last barrier;
    // writes complete mid-super so the pre-barrier lgkm drain is free.
    if (s < NSUPER - 1) WRITE_SLAB(buf ^ 1);
    if (s < NSUPER - 2) {
      xv0 = *(const float4*)(xbase + (s + 2) * 64);
      xv1 = *(const float4*)(xbase + (s + 2) * 64 + 4);
    }
    if (!oddw) {
      // even waves: chunk 2s then 2s+1, m-order 0,1,2,3
      CHUNK_HALF(0, 0, 0, buf, 0, 1, 2, 3);
      ISSUE(0, 2 * s + 1, 0);
      CHUNK_HALF(1, 1, 0, buf, 0, 1, 2, 3);
      ISSUE(1, 2 * s + 1, 1);
      CHUNK_HALF(0, 0, 1, buf, 0, 1, 2, 3);
      ISSUE(0, 2 * s + 2, 0);
      CHUNK_HALF(1, 1, 1, buf, 0, 1, 2, 3);
      ISSUE(1, 2 * s + 2, 1);
    } else {
      // odd waves: chunk 2s+1 then 2s, m-order 2,3,0,1 (de-phased)
      CHUNK_HALF(0, 0, 1, buf, 2, 3, 0, 1);
      ISSUE(0, 2 * s, 0);
      CHUNK_HALF(1, 1, 1, buf, 2, 3, 0, 1);
      ISSUE(1, 2 * s, 1);
      CHUNK_HALF(0, 0, 0, buf, 2, 3, 0, 1);
      ISSUE(0, 2 * s + 3, 0);
      CHUNK_HALF(1, 1, 0, buf, 2, 3, 0, 1);
      ISSUE(1, 2 * s + 3, 1);
    }
    SLAB_BARRIER();
  }
#undef ISSUE
#undef CH_M
#undef CHUNK_HALF
#undef WRITE_SLAB
#undef SLAB_BARRIER
  __syncthreads();  // full drain before overlaying epilogue LDS

  // ---------------- epilogue (h at scale 2^12 in acc; r6/r8-verified) -------
  float* eW2T = (float*)pool;              // [512][12] padded = 24576 B
  float* eStat = (float*)(pool + 24576);   // [8][64][2] = 4096 B
  float* eLog = (float*)(pool + 28672);    // [8][64][8] = 16384 B
  float* eMu = (float*)(pool + 45056);     // [64]
  float* eRs = (float*)(pool + 45312);     // [64]
  float* eFP = (float*)(pool + 45568);     // [16]

  // stage W2 (each thread owns one column h = tid)
  {
    float4 wa = *(const float4*)&W2[tid * 8];
    float4 wb = *(const float4*)&W2[tid * 8 + 4];
    *(float4*)&eW2T[tid * 12] = wa;
    *(float4*)&eW2T[tid * 12 + 4] = wb;
  }
  if (tid < 16) eFP[tid] = 0.0f;

  // h += b1 (scaled); per-column params from L2 (tiny + hot)
  float bb[4], lw[4], lb[4];
#pragma unroll
  for (int n = 0; n < 4; ++n) {
    int col = wv * 64 + n * 16 + l15;
    bb[n] = b1[col] * 4096.0f;
    lw[n] = lnw[col];
    lb[n] = lnb[col];
#pragma unroll
    for (int m = 0; m < 4; ++m)
#pragma unroll
      for (int r = 0; r < 4; ++r) acc[m][n][r] += bb[n];
  }

  // row stats: partial over this wave's 64 cols, deterministic combine
#pragma unroll
  for (int m = 0; m < 4; ++m) {
    float s1[4] = {0, 0, 0, 0};
    float s2[4] = {0, 0, 0, 0};
#pragma unroll
    for (int n = 0; n < 4; ++n)
#pragma unroll
      for (int r = 0; r < 4; ++r) {
        float vv = acc[m][n][r];
        s1[r] += vv;
        s2[r] = fmaf(vv, vv, s2[r]);
      }
#pragma unroll
    for (int d = 1; d < 16; d <<= 1)
#pragma unroll
      for (int r = 0; r < 4; ++r) {
        s1[r] += __shfl_xor(s1[r], d);
        s2[r] += __shfl_xor(s2[r], d);
      }
    if (l15 == 0) {
      int rb = m * 16 + l4 * 4;
#pragma unroll
      for (int r = 0; r < 4; ++r) {
        eStat[(wv * 64 + rb + r) * 2 + 0] = s1[r];
        eStat[(wv * 64 + rb + r) * 2 + 1] = s2[r];
      }
    }
  }
  __syncthreads();
  if (tid < BM) {
    float s1 = 0.0f, s2 = 0.0f;
#pragma unroll
    for (int w = 0; w < 8; ++w) {
      s1 += eStat[(w * 64 + tid) * 2 + 0];
      s2 += eStat[(w * 64 + tid) * 2 + 1];
    }
    float mu = s1 * (1.0f / 512.0f);
    float var = s2 * (1.0f / 512.0f) - mu * mu;
    eMu[tid] = mu;
    eRs[tid] = 1.0f / sqrtf(var + (1e-5f * 4096.0f * 4096.0f));
  }
  __syncthreads();

  // LN + exact-erf GELU + per-wave partial logits (per-r accumulation)
#pragma unroll
  for (int m = 0; m < 4; ++m) {
    int rb = m * 16 + l4 * 4;
#pragma unroll
    for (int r = 0; r < 4; ++r) {
      float mu_r = eMu[rb + r];
      float rs_r = eRs[rb + r];
      float lg[8];
#pragma unroll
      for (int e = 0; e < 8; ++e) lg[e] = 0.0f;
#pragma unroll
      for (int n = 0; n < 4; ++n) {
        int col = wv * 64 + n * 16 + l15;
        float hn = (acc[m][n][r] - mu_r) * rs_r;
        float y = fmaf(hn, lw[n], lb[n]);
        float g = 0.5f * y * (1.0f + erff(y * 0.70710678118654752440f));
        float4 w0 = *(const float4*)&eW2T[col * 12];
        float4 w1 = *(const float4*)&eW2T[col * 12 + 4];
        lg[0] = fmaf(g, w0.x, lg[0]);
        lg[1] = fmaf(g, w0.y, lg[1]);
        lg[2] = fmaf(g, w0.z, lg[2]);
        lg[3] = fmaf(g, w0.w, lg[3]);
        lg[4] = fmaf(g, w1.x, lg[4]);
        lg[5] = fmaf(g, w1.y, lg[5]);
        lg[6] = fmaf(g, w1.z, lg[6]);
        lg[7] = fmaf(g, w1.w, lg[7]);
      }
#pragma unroll
      for (int d = 1; d < 16; d <<= 1)
#pragma unroll
        for (int e = 0; e < 8; ++e) lg[e] += __shfl_xor(lg[e], d);
      if (l15 == 0) {
#pragma unroll
        for (int e = 0; e < 8; ++e) eLog[(wv * 64 + rb + r) * 8 + e] = lg[e];
      }
    }
  }
  __syncthreads();

  // top-2 + sparse softmax + write + load-balance partials
  if (tid < BM) {
    float v[8];
#pragma unroll
    for (int e = 0; e < 8; ++e) {
      float s = b2[e];
#pragma unroll
      for (int w = 0; w < 8; ++w) s += eLog[(w * 64 + tid) * 8 + e];
      v[e] = s;
    }
    float m1 = v[0];
    int i1 = 0;
#pragma unroll
    for (int e = 1; e < 8; ++e)
      if (v[e] > m1) { m1 = v[e]; i1 = e; }   // strict >: lowest index wins ties
    float m2 = -3.0e38f;
    int i2 = -1;
#pragma unroll
    for (int e = 0; e < 8; ++e)
      if (e != i1 && v[e] > m2) { m2 = v[e]; i2 = e; }
    float dd = expf(m2 - m1);
    float inv = 1.0f / (1.0f + dd);
    float wA = inv, wB = dd * inv;
    float o[8];
#pragma unroll
    for (int e = 0; e < 8; ++e)
      o[e] = (e == i1) ? wA : ((e == i2) ? wB : 0.0f);
    float4* op = (float4*)&out[(row0 + tid) * 8];
    op[0] = (float4){o[0], o[1], o[2], o[3]};
    op[1] = (float4){o[4], o[5], o[6], o[7]};
    atomicAdd(&eFP[i1], 1.0f);
    atomicAdd(&eFP[i2], 1.0f);
    atomicAdd(&eFP[8 + i1], wA);
    atomicAdd(&eFP[8 + i2], wB);
  }
  __syncthreads();
  if (tid < 16) atomicAdd(&gacc[tid], eFP[tid]);
}

// ---- finalize load-balance loss --------------------------------------------
__global__ void lb_final(const float* __restrict__ gacc, float* __restrict__ out) {
  if (threadIdx.x == 0) {
    const float invB = 1.0f / 65536.0f;
    float s = 0.0f;
#pragma unroll
    for (int e = 0; e < 8; ++e) s += (gacc[e] * invB) * (gacc[8 + e] * invB);
    out[(size_t)B_ROWS * E_DIM] = 0.01f * 8.0f * s;
  }
}

// ---- launch ----------------------------------------------------------------
extern "C" void kernel_launch(void* const* d_in, const int* in_sizes, int n_in,
                              void* d_out, int out_size, void* d_ws, size_t ws_size,
                              hipStream_t stream) {
  (void)in_sizes; (void)n_in; (void)out_size; (void)ws_size;
  const float* x = (const float*)d_in[0];
  const float* W1 = (const float*)d_in[1];
  const float* b1 = (const float*)d_in[2];
  const float* lnw = (const float*)d_in[3];
  const float* lnb = (const float*)d_in[4];
  const float* W2 = (const float*)d_in[5];
  const float* b2 = (const float*)d_in[6];
  float* out = (float*)d_out;
  f16* wh = (f16*)d_ws;
  f16* wl = wh + IMG_TOTAL;
  float* gacc = (float*)((char*)d_ws + GACC_OFF);  // ws needs ~2.1 MB

  zero_acc<<<1, 64, 0, stream>>>(gacc);
  prep_split<<<(D_DIM * H_DIM / 8) / 256, 256, 0, stream>>>(W1, wh, wl);
  fused_main<<<B_ROWS / BM, THREADS, 0, stream>>>(x, wh, wl, b1, lnw, lnb, W2, b2,
                                                  out, gacc);
  lb_final<<<1, 64, 0, stream>>>(gacc, out);
}

// Round 12
// 242.383 us; speedup vs baseline: 1.3107x; 1.1216x over previous
//
#include <hip/hip_runtime.h>
#include <cstdint>
#include <cstddef>

// ---------------------------------------------------------------------------
// GatingNetwork r12: wave tile 64x128 (4 waves, 256-thread blocks) -- doubles
// MFMA per A-ds_read vs r8's 64x64 (chip ds_reads halve; DS pipe 82%->41% of
// MFMA load). R6-proven per-chunk slabs + rolling 2-set B pipe + raw lgkm-only
// barriers. 128 AGPR acc + 64 VGPR B-sets -> 2 waves/SIMD, 2 blocks/CU
// (independent barriers = natural block-level de-phasing).
// Numerics (r1-r11 verified): A=64x hi/lo fp16, B=64w hi/lo fp16 (lo x2^8);
// 3-product Markidis MFMA 16x16x32; h at scale 2^12; fused LN/GELU/top2.
// ---------------------------------------------------------------------------

typedef _Float16 f16;
typedef _Float16 f16x8 __attribute__((ext_vector_type(8)));
typedef float f32x4 __attribute__((ext_vector_type(4)));

#define B_ROWS 65536
#define D_DIM 1024
#define H_DIM 512
#define E_DIM 8
#define BM 64
#define BK 32
#define THREADS 256
#define NCHUNK 32
#define LDPX 40                          // slab row stride in halves (80 B)
#define SLABH 2560                       // 64 rows x 40 halves (one image)
#define BUFH 5120                        // hi + lo per buffer
#define IMG_CH (H_DIM * BK)              // 16384 halves per K-chunk B image
#define IMG_TOTAL (32 * IMG_CH)          // 1 MB per image
#define GACC_OFF ((size_t)2 * IMG_TOTAL * sizeof(f16))  // 2 MB

// ---- prep: split W1 into fp16 hi/lo images in MFMA B-fragment order --------
__global__ void prep_split(const float* __restrict__ W1,
                           f16* __restrict__ wh, f16* __restrict__ wl) {
  int id = blockIdx.x * 256 + threadIdx.x;   // 65536 threads
  int h = id & (H_DIM - 1);
  int kg = id >> 9;                          // 0..127
  int c = kg >> 2;
  int kk0 = (kg & 3) * 8;
  int k0 = kg * 8;
  f16x8 hv, lv;
#pragma unroll
  for (int j = 0; j < 8; ++j) {
    float v = W1[(size_t)(k0 + j) * H_DIM + h] * 64.0f;
    f16 hi = (f16)v;
    hv[j] = hi;
    lv[j] = (f16)((v - (float)hi) * 256.0f);  // residual pre-scaled 2^8
  }
  size_t o = (size_t)c * IMG_CH + (size_t)h * BK + kk0;
  *(f16x8*)&wh[o] = hv;
  *(f16x8*)&wl[o] = lv;
}

__global__ void zero_acc(float* __restrict__ acc) {
  if (threadIdx.x < 16) acc[threadIdx.x] = 0.0f;
}

// ---- main fused kernel -----------------------------------------------------
__global__ __launch_bounds__(THREADS, 2) void fused_main(
    const float* __restrict__ x,
    const f16* __restrict__ wh, const f16* __restrict__ wl,
    const float* __restrict__ b1, const float* __restrict__ lnw,
    const float* __restrict__ lnb, const float* __restrict__ W2,
    const float* __restrict__ b2, float* __restrict__ out,
    float* __restrict__ gacc) {
  // GEMM uses [0,20480) (2 x-slab buffers). Epilogue overlays [0,35584).
  __shared__ __align__(16) char pool[35584];
  f16* sx = (f16*)pool;

  const int tid = threadIdx.x;
  const int lane = tid & 63;
  const int wv = tid >> 6;        // 0..3 : wave owns cols wv*128..+127, all 64 rows
  const int l15 = lane & 15;
  const int l4 = lane >> 4;       // 0..3
  const int64_t row0 = (int64_t)blockIdx.x * BM;

  // staging: thread stages row tid>>2, 8 floats at k-offset (tid&3)*8
  const int srow = tid >> 2;
  const int koff = (tid & 3) * 8;
  const int swo = srow * LDPX + koff;
  const float* xbase = x + (row0 + srow) * D_DIM + koff;

  // B lane base (fragment-order image, r2-verified): col = wv*128 + ...
  const f16* whp = wh + (wv * 128 + l15) * BK + l4 * 8;

  f32x4 acc[4][8];
#pragma unroll
  for (int m = 0; m < 4; ++m)
#pragma unroll
    for (int n = 0; n < 8; ++n) acc[m][n] = (f32x4){0.f, 0.f, 0.f, 0.f};

  // two half-chunk B register sets: [set][0..3]=hi frags, [4..7]=lo frags
  // (half = 64-col group within the wave's 128 cols)
  f16x8 setB[2][8];

#define ISSUE(si, C, half)                                                    \
  do {                                                                        \
    const f16* p = whp + (size_t)((C) & 31) * IMG_CH + (half) * 2048;         \
    setB[si][0] = *(const f16x8*)(p);                                         \
    setB[si][1] = *(const f16x8*)(p + 512);                                   \
    setB[si][2] = *(const f16x8*)(p + 1024);                                  \
    setB[si][3] = *(const f16x8*)(p + 1536);                                  \
    setB[si][4] = *(const f16x8*)(p + IMG_TOTAL);                             \
    setB[si][5] = *(const f16x8*)(p + IMG_TOTAL + 512);                       \
    setB[si][6] = *(const f16x8*)(p + IMG_TOTAL + 1024);                      \
    setB[si][7] = *(const f16x8*)(p + IMG_TOTAL + 1536);                      \
  } while (0)

  // one m-row of a 64-col half: 2 ds_read_b128 + pk_mul + 12 MFMA
  // (acc rotated across 4 n's -> dependent spacing 4)
#define CH_M(si, NH, bufv, MM)                                                \
  do {                                                                        \
    const int ao = (bufv)*BUFH + ((MM)*16 + l15) * LDPX + l4 * 8;             \
    f16x8 ah = *(const f16x8*)&sx[ao];                                        \
    f16x8 al = *(const f16x8*)&sx[ao + SLABH];                                \
    f16x8 ahs;                                                                \
    _Pragma("unroll") for (int q = 0; q < 8; ++q) ahs[q] =                    \
        ah[q] * (f16)0.00390625f;                                             \
    _Pragma("unroll") for (int n = 0; n < 4; ++n)                             \
      acc[MM][(NH)*4 + n] = __builtin_amdgcn_mfma_f32_16x16x32_f16(           \
          ah, setB[si][n], acc[MM][(NH)*4 + n], 0, 0, 0);                     \
    _Pragma("unroll") for (int n = 0; n < 4; ++n)                             \
      acc[MM][(NH)*4 + n] = __builtin_amdgcn_mfma_f32_16x16x32_f16(           \
          al, setB[si][n], acc[MM][(NH)*4 + n], 0, 0, 0);                     \
    _Pragma("unroll") for (int n = 0; n < 4; ++n)                             \
      acc[MM][(NH)*4 + n] = __builtin_amdgcn_mfma_f32_16x16x32_f16(           \
          ahs, setB[si][4 + n], acc[MM][(NH)*4 + n], 0, 0, 0);                \
  } while (0)

#define HALF(si, NH, bufv)                                                    \
  do {                                                                        \
    __builtin_amdgcn_s_setprio(1);                                            \
    CH_M(si, NH, bufv, 0);                                                    \
    CH_M(si, NH, bufv, 1);                                                    \
    CH_M(si, NH, bufv, 2);                                                    \
    CH_M(si, NH, bufv, 3);                                                    \
    __builtin_amdgcn_s_setprio(0);                                            \
  } while (0)

#define WRITE_SLAB(bufv)                                                      \
  do {                                                                        \
    float vv[8] = {xv0.x, xv0.y, xv0.z, xv0.w, xv1.x, xv1.y, xv1.z, xv1.w};   \
    f16x8 hv, lv;                                                             \
    _Pragma("unroll") for (int q = 0; q < 8; ++q) {                           \
      float t = vv[q] * 64.0f;                                                \
      f16 hh = (f16)t;                                                        \
      hv[q] = hh;                                                             \
      lv[q] = (f16)(t - (float)hh);                                           \
    }                                                                         \
    *(f16x8*)&sx[(bufv)*BUFH + swo] = hv;                                     \
    *(f16x8*)&sx[(bufv)*BUFH + SLABH + swo] = lv;                             \
  } while (0)

  // raw barrier: drain only LDS ops, keep global loads in flight (T4)
#define SLAB_BARRIER()                                                        \
  do {                                                                        \
    asm volatile("s_waitcnt lgkmcnt(0)" ::: "memory");                        \
    __builtin_amdgcn_s_barrier();                                             \
    __builtin_amdgcn_sched_barrier(0);                                        \
  } while (0)

  // ---- prologue: slab chunk0, B sets for chunk0 halves, xv <- chunk1 ------
  float4 xv0 = *(const float4*)(xbase);
  float4 xv1 = *(const float4*)(xbase + 4);
  WRITE_SLAB(0);
  ISSUE(0, 0, 0);
  ISSUE(1, 0, 1);
  xv0 = *(const float4*)(xbase + 32);
  xv1 = *(const float4*)(xbase + 36);
  SLAB_BARRIER();

  for (int c = 0; c < NCHUNK; ++c) {
    const int buf = c & 1;
    HALF(0, 0, buf);              // cols wv*128+0..63   (set issued 1 chunk ago)
    ISSUE(0, c + 1, 0);           // refill set0 for chunk c+1
    HALF(1, 1, buf);              // cols wv*128+64..127
    ISSUE(1, c + 1, 1);           // refill set1 for chunk c+1
    WRITE_SLAB(buf ^ 1);          // slab chunk c+1 (xv loaded last iteration)
    xv0 = *(const float4*)(xbase + ((c + 2) & 31) * 32);     // x for chunk c+2
    xv1 = *(const float4*)(xbase + ((c + 2) & 31) * 32 + 4);
    SLAB_BARRIER();
  }
#undef ISSUE
#undef CH_M
#undef HALF
#undef WRITE_SLAB
#undef SLAB_BARRIER
  __syncthreads();  // full drain before overlaying epilogue LDS

  // ---------------- epilogue (h at scale 2^12 in acc) -----------------------
  float* eW2T = (float*)pool;              // [512][12] padded = 24576 B
  float* eStat = (float*)(pool + 24576);   // [4][64][2] = 2048 B
  float* eLog = (float*)(pool + 26624);    // [4][64][8] = 8192 B
  float* eMu = (float*)(pool + 34816);     // [64]
  float* eRs = (float*)(pool + 35072);     // [64]
  float* eFP = (float*)(pool + 35328);     // [16]

  // stage W2 (256 threads cover 512 cols in 2 passes)
  for (int i = tid; i < H_DIM; i += THREADS) {
    float4 wa = *(const float4*)&W2[i * 8];
    float4 wb = *(const float4*)&W2[i * 8 + 4];
    *(float4*)&eW2T[i * 12] = wa;
    *(float4*)&eW2T[i * 12 + 4] = wb;
  }
  if (tid < 16) eFP[tid] = 0.0f;

  // h += b1 (scaled); per-column params from L2 (8 n-frags per thread)
  float bb[8], lw[8], lb[8];
#pragma unroll
  for (int n = 0; n < 8; ++n) {
    int col = wv * 128 + n * 16 + l15;
    bb[n] = b1[col] * 4096.0f;
    lw[n] = lnw[col];
    lb[n] = lnb[col];
#pragma unroll
    for (int m = 0; m < 4; ++m)
#pragma unroll
      for (int r = 0; r < 4; ++r) acc[m][n][r] += bb[n];
  }

  // row stats: partial over this wave's 128 cols, deterministic combine
#pragma unroll
  for (int m = 0; m < 4; ++m) {
    float s1[4] = {0, 0, 0, 0};
    float s2[4] = {0, 0, 0, 0};
#pragma unroll
    for (int n = 0; n < 8; ++n)
#pragma unroll
      for (int r = 0; r < 4; ++r) {
        float vv = acc[m][n][r];
        s1[r] += vv;
        s2[r] = fmaf(vv, vv, s2[r]);
      }
#pragma unroll
    for (int d = 1; d < 16; d <<= 1)
#pragma unroll
      for (int r = 0; r < 4; ++r) {
        s1[r] += __shfl_xor(s1[r], d);
        s2[r] += __shfl_xor(s2[r], d);
      }
    if (l15 == 0) {
      int rb = m * 16 + l4 * 4;
#pragma unroll
      for (int r = 0; r < 4; ++r) {
        eStat[(wv * 64 + rb + r) * 2 + 0] = s1[r];
        eStat[(wv * 64 + rb + r) * 2 + 1] = s2[r];
      }
    }
  }
  __syncthreads();
  if (tid < BM) {
    float s1 = 0.0f, s2 = 0.0f;
#pragma unroll
    for (int w = 0; w < 4; ++w) {
      s1 += eStat[(w * 64 + tid) * 2 + 0];
      s2 += eStat[(w * 64 + tid) * 2 + 1];
    }
    float mu = s1 * (1.0f / 512.0f);
    float var = s2 * (1.0f / 512.0f) - mu * mu;
    eMu[tid] = mu;
    eRs[tid] = 1.0f / sqrtf(var + (1e-5f * 4096.0f * 4096.0f));
  }
  __syncthreads();

  // LN + exact-erf GELU + per-wave partial logits (per-r accumulation)
#pragma unroll
  for (int m = 0; m < 4; ++m) {
    int rb = m * 16 + l4 * 4;
#pragma unroll
    for (int r = 0; r < 4; ++r) {
      float mu_r = eMu[rb + r];
      float rs_r = eRs[rb + r];
      float lg[8];
#pragma unroll
      for (int e = 0; e < 8; ++e) lg[e] = 0.0f;
#pragma unroll
      for (int n = 0; n < 8; ++n) {
        int col = wv * 128 + n * 16 + l15;
        float hn = (acc[m][n][r] - mu_r) * rs_r;
        float y = fmaf(hn, lw[n], lb[n]);
        float g = 0.5f * y * (1.0f + erff(y * 0.70710678118654752440f));
        float4 w0 = *(const float4*)&eW2T[col * 12];
        float4 w1 = *(const float4*)&eW2T[col * 12 + 4];
        lg[0] = fmaf(g, w0.x, lg[0]);
        lg[1] = fmaf(g, w0.y, lg[1]);
        lg[2] = fmaf(g, w0.z, lg[2]);
        lg[3] = fmaf(g, w0.w, lg[3]);
        lg[4] = fmaf(g, w1.x, lg[4]);
        lg[5] = fmaf(g, w1.y, lg[5]);
        lg[6] = fmaf(g, w1.z, lg[6]);
        lg[7] = fmaf(g, w1.w, lg[7]);
      }
#pragma unroll
      for (int d = 1; d < 16; d <<= 1)
#pragma unroll
        for (int e = 0; e < 8; ++e) lg[e] += __shfl_xor(lg[e], d);
      if (l15 == 0) {
#pragma unroll
        for (int e = 0; e < 8; ++e) eLog[(wv * 64 + rb + r) * 8 + e] = lg[e];
      }
    }
  }
  __syncthreads();

  // top-2 + sparse softmax + write + load-balance partials
  if (tid < BM) {
    float v[8];
#pragma unroll
    for (int e = 0; e < 8; ++e) {
      float s = b2[e];
#pragma unroll
      for (int w = 0; w < 4; ++w) s += eLog[(w * 64 + tid) * 8 + e];
      v[e] = s;
    }
    float m1 = v[0];
    int i1 = 0;
#pragma unroll
    for (int e = 1; e < 8; ++e)
      if (v[e] > m1) { m1 = v[e]; i1 = e; }   // strict >: lowest index wins ties
    float m2 = -3.0e38f;
    int i2 = -1;
#pragma unroll
    for (int e = 0; e < 8; ++e)
      if (e != i1 && v[e] > m2) { m2 = v[e]; i2 = e; }
    float dd = expf(m2 - m1);
    float inv = 1.0f / (1.0f + dd);
    float wA = inv, wB = dd * inv;
    float o[8];
#pragma unroll
    for (int e = 0; e < 8; ++e)
      o[e] = (e == i1) ? wA : ((e == i2) ? wB : 0.0f);
    float4* op = (float4*)&out[(row0 + tid) * 8];
    op[0] = (float4){o[0], o[1], o[2], o[3]};
    op[1] = (float4){o[4], o[5], o[6], o[7]};
    atomicAdd(&eFP[i1], 1.0f);
    atomicAdd(&eFP[i2], 1.0f);
    atomicAdd(&eFP[8 + i1], wA);
    atomicAdd(&eFP[8 + i2], wB);
  }
  __syncthreads();
  if (tid < 16) atomicAdd(&gacc[tid], eFP[tid]);
}

// ---- finalize load-balance loss --------------------------------------------
__global__ void lb_final(const float* __restrict__ gacc, float* __restrict__ out) {
  if (threadIdx.x == 0) {
    const float invB = 1.0f / 65536.0f;
    float s = 0.0f;
#pragma unroll
    for (int e = 0; e < 8; ++e) s += (gacc[e] * invB) * (gacc[8 + e] * invB);
    out[(size_t)B_ROWS * E_DIM] = 0.01f * 8.0f * s;
  }
}

// ---- launch ----------------------------------------------------------------
extern "C" void kernel_launch(void* const* d_in, const int* in_sizes, int n_in,
                              void* d_out, int out_size, void* d_ws, size_t ws_size,
                              hipStream_t stream) {
  (void)in_sizes; (void)n_in; (void)out_size; (void)ws_size;
  const float* x = (const float*)d_in[0];
  const float* W1 = (const float*)d_in[1];
  const float* b1 = (const float*)d_in[2];
  const float* lnw = (const float*)d_in[3];
  const float* lnb = (const float*)d_in[4];
  const float* W2 = (const float*)d_in[5];
  const float* b2 = (const float*)d_in[6];
  float* out = (float*)d_out;
  f16* wh = (f16*)d_ws;
  f16* wl = wh + IMG_TOTAL;
  float* gacc = (float*)((char*)d_ws + GACC_OFF);  // ws needs ~2.1 MB

  zero_acc<<<1, 64, 0, stream>>>(gacc);
  prep_split<<<(D_DIM * H_DIM / 8) / 256, 256, 0, stream>>>(W1, wh, wl);
  fused_main<<<B_ROWS / BM, THREADS, 0, stream>>>(x, wh, wl, b1, lnw, lnb, W2, b2,
                                                  out, gacc);
  lb_final<<<1, 64, 0, stream>>>(gacc, out);
}